// Round 14
// baseline (67.279 us; speedup 1.0000x reference)
//
#include <hip/hip_runtime.h>
#include <hip/hip_bf16.h>

typedef __attribute__((ext_vector_type(8))) short bf16x8;
typedef __attribute__((ext_vector_type(4))) float f32x4;

#define NB 1024
#define ND 256
#define MARGINF 0.3f
#define BIGV 1e9f
#define D2R 0.017453292519943295f
#define HD2R 0.008726646259971648f

// haversine 'a' thresholds: sin^2(T/(2*6371000)) (validated rounds 1-13)
#define A_POS 3.8495040e-12f   // 25 m
#define A_NEG 6.1592064e-11f   // 100 m

// flags layout (19 floats, memset to 0 each call):
//   [0]=gsum  [1]=gcnt  [2]=done-counter  [3..18]=per-row-group counters
#define F_GSUM 0
#define F_GCNT 1
#define F_DONE 2
#define F_GRP  3

__device__ __forceinline__ float d4(float4 a, float4 b, float acc) {
    return fmaf(a.x,b.x, fmaf(a.y,b.y, fmaf(a.z,b.z, fmaf(a.w,b.w, acc))));
}

__device__ __forceinline__ void splitHL(float4 v0, float4 v1, bf16x8& H, bf16x8& L) {
    float f[8] = {v0.x, v0.y, v0.z, v0.w, v1.x, v1.y, v1.z, v1.w};
    #pragma unroll
    for (int q = 0; q < 8; ++q) {
        __hip_bfloat16 h = __float2bfloat16(f[q]);
        float hf = __bfloat162float(h);
        __hip_bfloat16 l = __float2bfloat16(f[q] - hf);
        H[q] = *(short*)&h;
        L[q] = *(short*)&l;
    }
}

// One fused kernel: r11 gram body (2x2 waves, 12 MFMA / 4 splitHL per wave per
// k-window) + per-row-group last-block rows scan + last-scanner loss emit.
__global__ __launch_bounds__(256) void gram_fused(
    const float* __restrict__ emb, const float* __restrict__ gps,
    float* __restrict__ sEnc, float* __restrict__ pP,
    float* __restrict__ flags, float* __restrict__ out)
{
    __shared__ float  sSqI[64], sSqJ[64];
    __shared__ float4 sGI[64], sGJ[64];
    __shared__ float  sRed[64][33];
    __shared__ float  sT[4], sV[4];
    __shared__ int    sLast;

    const int tid = threadIdx.x, lane = tid & 63, w = tid >> 6;
    const int wr = w >> 1, wc = w & 1;
    const int ib = blockIdx.x & 15, jb = blockIdx.x >> 4;
    const int i0 = ib*64, j0 = jb*64;
    const int lr = lane & 15, lk = lane >> 4;
    const float4* __restrict__ emb4 = (const float4*)emb;

    // ---- prologue: row norms (exact fp32) + gps scalars ----
    {
        const int half = tid & 1, r = (tid >> 1) & 63;
        const int base = (tid < 128) ? i0 : j0;
        const float4* rp = emb4 + (size_t)(base + r)*64 + half*32;
        float s = 0.f;
        #pragma unroll
        for (int q = 0; q < 32; ++q) s = d4(rp[q], rp[q], s);
        s += __shfl_xor(s, 1);
        if (half == 0) { if (tid < 128) sSqI[r] = s; else sSqJ[r] = s; }
    }
    if (tid < 128) {
        const int r = tid & 63;
        const int base = (tid < 64) ? i0 : j0;
        float2 g = ((const float2*)gps)[base + r];
        float4 gi = make_float4(g.x, g.y, cosf(g.x * D2R), 0.f);
        if (tid < 64) sGI[r] = gi; else sGJ[r] = gi;
    }
    __syncthreads();

    // ---- MFMA loop (r11-exact): 8 k-windows x {8 loads -> 4 splits -> 12 MFMAs} ----
    f32x4 acc[2][2] = {};
    #pragma unroll 2
    for (int k8 = 0; k8 < 8; ++k8) {
        const int co = k8*8 + lk*2;
        const float4* pa0 = emb4 + (size_t)(i0 + wr*32      + lr)*64 + co;
        const float4* pa1 = emb4 + (size_t)(i0 + wr*32 + 16 + lr)*64 + co;
        const float4* pb0 = emb4 + (size_t)(j0 + wc*32      + lr)*64 + co;
        const float4* pb1 = emb4 + (size_t)(j0 + wc*32 + 16 + lr)*64 + co;
        bf16x8 a0H,a0L,a1H,a1L,b0H,b0L,b1H,b1L;
        splitHL(pa0[0], pa0[1], a0H, a0L);
        splitHL(pa1[0], pa1[1], a1H, a1L);
        splitHL(pb0[0], pb0[1], b0H, b0L);
        splitHL(pb1[0], pb1[1], b1H, b1L);
        acc[0][0] = __builtin_amdgcn_mfma_f32_16x16x32_bf16(a0H, b0H, acc[0][0], 0,0,0);
        acc[0][1] = __builtin_amdgcn_mfma_f32_16x16x32_bf16(a0H, b1H, acc[0][1], 0,0,0);
        acc[1][0] = __builtin_amdgcn_mfma_f32_16x16x32_bf16(a1H, b0H, acc[1][0], 0,0,0);
        acc[1][1] = __builtin_amdgcn_mfma_f32_16x16x32_bf16(a1H, b1H, acc[1][1], 0,0,0);
        acc[0][0] = __builtin_amdgcn_mfma_f32_16x16x32_bf16(a0L, b0H, acc[0][0], 0,0,0);
        acc[0][1] = __builtin_amdgcn_mfma_f32_16x16x32_bf16(a0L, b1H, acc[0][1], 0,0,0);
        acc[1][0] = __builtin_amdgcn_mfma_f32_16x16x32_bf16(a1L, b0H, acc[1][0], 0,0,0);
        acc[1][1] = __builtin_amdgcn_mfma_f32_16x16x32_bf16(a1L, b1H, acc[1][1], 0,0,0);
        acc[0][0] = __builtin_amdgcn_mfma_f32_16x16x32_bf16(a0H, b0L, acc[0][0], 0,0,0);
        acc[0][1] = __builtin_amdgcn_mfma_f32_16x16x32_bf16(a0H, b1L, acc[0][1], 0,0,0);
        acc[1][0] = __builtin_amdgcn_mfma_f32_16x16x32_bf16(a1H, b0L, acc[1][0], 0,0,0);
        acc[1][1] = __builtin_amdgcn_mfma_f32_16x16x32_bf16(a1H, b1L, acc[1][1], 0,0,0);
    }

    // ---- epilogue: d^2, masks, sEnc encode, per-row pmax partials ----
    float sqj[2]; float4 gj2[2];
    sqj[0] = sSqJ[wc*32 + lr];      gj2[0] = sGJ[wc*32 + lr];
    sqj[1] = sSqJ[wc*32 + 16 + lr]; gj2[1] = sGJ[wc*32 + 16 + lr];

    #pragma unroll
    for (int fi = 0; fi < 2; ++fi) {
        #pragma unroll
        for (int r = 0; r < 4; ++r) {
            const int rl = wr*32 + fi*16 + lk*4 + r;
            const int gi = i0 + rl;
            const float sqi = sSqI[rl];
            const float4 gvi = sGI[rl];
            float pmax = -1.f;
            #pragma unroll
            for (int fj = 0; fj < 2; ++fj) {
                const int gj = j0 + wc*32 + fj*16 + lr;
                float d2v = sqi + sqj[fj] - 2.f*acc[fi][fj][r];
                d2v = d2v > 0.f ? d2v : 0.f;
                const float sla = sinf((gj2[fj].x - gvi.x) * HD2R);
                const float slo = sinf((gj2[fj].y - gvi.y) * HD2R);
                const float hav = fmaf(sla, sla, (gvi.z * gj2[fj].z) * (slo*slo));
                const bool pos = (hav < A_POS) && (gi != gj);
                const bool neg = (hav > A_NEG);
                pmax = fmaxf(pmax, pos ? d2v : -1.f);
                sEnc[(size_t)gi*NB + gj] = neg ? d2v : BIGV;
            }
            sRed[rl][lr + 16*wc] = pmax;
        }
    }
    __syncthreads();
    if (tid < 64) {
        float m = sRed[tid][0];
        #pragma unroll
        for (int c = 1; c < 32; ++c) m = fmaxf(m, sRed[tid][c]);
        pP[(i0 + tid)*16 + jb] = m;
    }

    // ---- completion: last block of row-group ib scans its 64 rows ----
    __threadfence();                 // release sEnc/pP (device scope, G16)
    __syncthreads();
    if (tid == 0) {
        const unsigned old = atomicAdd((unsigned*)&flags[F_GRP + ib], 1u);
        sLast = (old == 15u) ? 1 : 0;
    }
    __syncthreads();
    if (!sLast) return;              // block-uniform exit

    __threadfence();                 // acquire before reading sEnc/pP
    float accT = 0.f, accV = 0.f;
    #pragma unroll 2
    for (int p = 0; p < 16; ++p) {
        const int i = i0 + p*4 + w;  // wave w owns row i this pass
        float pv = pP[i*16 + (lane & 15)];
        #pragma unroll
        for (int off = 1; off < 16; off <<= 1) pv = fmaxf(pv, __shfl_xor(pv, off));
        const float dap2 = pv;
        const bool has_pos = dap2 > -0.5f;
        float lo2 = -1.f, hi2 = -1.f;
        if (has_pos) { const float hb = sqrtf(dap2) + MARGINF; lo2 = dap2; hi2 = hb*hb; }

        float nmin = BIGV, smin = BIGV;
        const float4* __restrict__ row = (const float4*)sEnc + (size_t)i*256;
        #pragma unroll
        for (int pss = 0; pss < 4; ++pss) {
            const float4 x = row[pss*64 + lane];
            #pragma unroll
            for (int q = 0; q < 4; ++q) {
                const float xc = (q==0) ? x.x : (q==1) ? x.y : (q==2) ? x.z : x.w;
                nmin = fminf(nmin, xc);
                smin = fminf(smin, (xc > lo2 && xc < hi2) ? xc : BIGV);
            }
        }
        #pragma unroll
        for (int off = 1; off < 64; off <<= 1) {
            nmin = fminf(nmin, __shfl_xor(nmin, off));
            smin = fminf(smin, __shfl_xor(smin, off));
        }
        if (lane == 0) {
            const bool has_neg  = nmin < 0.5f*BIGV;
            const bool has_semi = smin < 0.5f*BIGV;
            const float dan2 = has_semi ? smin : nmin;
            const float dap  = has_pos ? sqrtf(dap2) : 0.f;
            float t = dap - sqrtf(dan2) + MARGINF;
            t = t > 0.f ? t : 0.f;
            const bool valid = has_pos && has_neg;
            accT += valid ? t : 0.f;
            accV += valid ? 1.f : 0.f;
        }
    }
    if (lane == 0) { sT[w] = accT; sV[w] = accV; }
    __syncthreads();
    if (tid == 0) {
        const float st = sT[0]+sT[1]+sT[2]+sT[3];
        const float sv = sV[0]+sV[1]+sV[2]+sV[3];
        atomicAdd(&flags[F_GSUM], st);
        atomicAdd(&flags[F_GCNT], sv);
        __threadfence();
        const unsigned old2 = atomicAdd((unsigned*)&flags[F_DONE], 1u);
        if (old2 == 15u) {           // last scanner emits the loss
            const float t = atomicAdd(&flags[F_GSUM], 0.f);
            const float v = atomicAdd(&flags[F_GCNT], 0.f);
            out[0] = t / fmaxf(v, 1.f);
        }
    }
}

extern "C" void kernel_launch(void* const* d_in, const int* in_sizes, int n_in,
                              void* d_out, int out_size, void* d_ws, size_t ws_size,
                              hipStream_t stream) {
    const float* emb = (const float*)d_in[0];   // [1024,256] f32
    const float* gps = (const float*)d_in[1];   // [1024,2]  f32
    float* ws = (float*)d_ws;

    float* sEnc  = ws;                    // 1024*1024 f32 = 4 MB
    float* pP    = ws + 1048576;          // 1024*16
    float* flags = pP + 16384;            // 19 floats

    hipMemsetAsync(flags, 0, 19*sizeof(float), stream);
    gram_fused<<<256, 256, 0, stream>>>(emb, gps, sEnc, pP, flags, (float*)d_out);
}

// Round 15
// 38.656 us; speedup vs baseline: 1.7404x; 1.7404x over previous
//
#include <hip/hip_runtime.h>
#include <hip/hip_bf16.h>

typedef __attribute__((ext_vector_type(8))) short bf16x8;
typedef __attribute__((ext_vector_type(4))) float f32x4;

#define NB 1024
#define ND 256
#define MARGINF 0.3f
#define BIGV 1e9f
#define D2R 0.017453292519943295f
#define HD2R 0.008726646259971648f

// haversine 'a' thresholds: sin^2(T/(2*6371000)) (validated rounds 1-14)
#define A_POS 3.8495040e-12f   // 25 m
#define A_NEG 6.1592064e-11f   // 100 m

__device__ __forceinline__ float d4(float4 a, float4 b, float acc) {
    return fmaf(a.x,b.x, fmaf(a.y,b.y, fmaf(a.z,b.z, fmaf(a.w,b.w, acc))));
}

// K0: build bf16 H/L panels + per-point {norm, lat, lon, cos}; zero flags.
__global__ __launch_bounds__(256) void prep_kernel(
    const float* __restrict__ emb, const float* __restrict__ gps,
    unsigned short* __restrict__ Hp, unsigned short* __restrict__ Lp,
    float4* __restrict__ prep, float* __restrict__ flags)
{
    const int tid = threadIdx.x;
    if (blockIdx.x == 0 && tid < 3) flags[tid] = 0.f;   // gsum, gcnt, done
    const int row = blockIdx.x*16 + (tid >> 4);
    const int kk  = tid & 15;
    const float4* r4 = (const float4*)emb + (size_t)row*64;
    float s = 0.f;
    #pragma unroll
    for (int c = 0; c < 4; ++c) {
        float4 v = r4[kk + 16*c];
        s = d4(v, v, s);
        float fv[4] = {v.x, v.y, v.z, v.w};
        unsigned short hh[4], ll[4];
        #pragma unroll
        for (int q = 0; q < 4; ++q) {
            __hip_bfloat16 h = __float2bfloat16(fv[q]);
            float hf = __bfloat162float(h);
            __hip_bfloat16 l = __float2bfloat16(fv[q] - hf);
            hh[q] = *(unsigned short*)&h;
            ll[q] = *(unsigned short*)&l;
        }
        *(ushort4*)(Hp + (size_t)row*ND + 4*(kk + 16*c)) = make_ushort4(hh[0],hh[1],hh[2],hh[3]);
        *(ushort4*)(Lp + (size_t)row*ND + 4*(kk + 16*c)) = make_ushort4(ll[0],ll[1],ll[2],ll[3]);
    }
    #pragma unroll
    for (int off = 1; off < 16; off <<= 1) s += __shfl_xor(s, off);
    if (kk == 0) {
        float2 g = ((const float2*)gps)[row];
        prep[row] = make_float4(s, g.x, g.y, cosf(g.x * D2R));
    }
}

// K1: MFMA Gram from prebuilt panels. 512 blocks (2/CU -> 2 waves/SIMD),
// tile 64x32, wave = 32x16. Per k-window: 6 loads + 6 MFMAs, zero split VALU.
// G = HH' + LH' + HL'; d^2 = norm_i + norm_j - 2G (exact fp32 norms).
__global__ __launch_bounds__(256) void gram_mfma(
    const unsigned short* __restrict__ Hp, const unsigned short* __restrict__ Lp,
    const float4* __restrict__ prep, float* __restrict__ sEnc, float* __restrict__ pP)
{
    __shared__ float4 sPI[64], sPJ[32];    // {norm, lat, lon, cos}
    __shared__ float  sRed[64][33];

    const int tid = threadIdx.x, lane = tid & 63, w = tid >> 6;
    const int wr = w >> 1, wc = w & 1;
    const int ib = blockIdx.x & 15, jb = blockIdx.x >> 4;   // 16 x 32
    const int i0 = ib*64, j0 = jb*32;
    const int lr = lane & 15, lk = lane >> 4;

    if (tid < 64) sPI[tid] = prep[i0 + tid];
    else if (tid < 96) sPJ[tid - 64] = prep[j0 + tid - 64];
    __syncthreads();

    const short* Hs = (const short*)Hp;
    const short* Ls = (const short*)Lp;
    const int rA0 = i0 + wr*32 + lr, rA1 = rA0 + 16, rB = j0 + wc*16 + lr;

    f32x4 acc0 = {}, acc1 = {};
    #pragma unroll 2
    for (int k8 = 0; k8 < 8; ++k8) {
        const int off = k8*32 + lk*8;
        bf16x8 aH0 = *(const bf16x8*)(Hs + (size_t)rA0*ND + off);
        bf16x8 aH1 = *(const bf16x8*)(Hs + (size_t)rA1*ND + off);
        bf16x8 aL0 = *(const bf16x8*)(Ls + (size_t)rA0*ND + off);
        bf16x8 aL1 = *(const bf16x8*)(Ls + (size_t)rA1*ND + off);
        bf16x8 bH  = *(const bf16x8*)(Hs + (size_t)rB *ND + off);
        bf16x8 bL  = *(const bf16x8*)(Ls + (size_t)rB *ND + off);
        acc0 = __builtin_amdgcn_mfma_f32_16x16x32_bf16(aH0, bH, acc0, 0,0,0);
        acc1 = __builtin_amdgcn_mfma_f32_16x16x32_bf16(aH1, bH, acc1, 0,0,0);
        acc0 = __builtin_amdgcn_mfma_f32_16x16x32_bf16(aL0, bH, acc0, 0,0,0);
        acc1 = __builtin_amdgcn_mfma_f32_16x16x32_bf16(aL1, bH, acc1, 0,0,0);
        acc0 = __builtin_amdgcn_mfma_f32_16x16x32_bf16(aH0, bL, acc0, 0,0,0);
        acc1 = __builtin_amdgcn_mfma_f32_16x16x32_bf16(aH1, bL, acc1, 0,0,0);
    }

    // epilogue: d^2, masks, sEnc encode, per-(row, jb) pmax partials
    const int gj = j0 + wc*16 + lr;
    const float4 pj = sPJ[wc*16 + lr];

    #pragma unroll
    for (int fi = 0; fi < 2; ++fi) {
        const f32x4 a = fi ? acc1 : acc0;
        #pragma unroll
        for (int r = 0; r < 4; ++r) {
            const int rl = wr*32 + fi*16 + lk*4 + r;
            const int gi = i0 + rl;
            const float4 pi = sPI[rl];
            float d2v = pi.x + pj.x - 2.f*a[r];
            d2v = d2v > 0.f ? d2v : 0.f;
            const float sla = sinf((pj.y - pi.y) * HD2R);
            const float slo = sinf((pj.z - pi.z) * HD2R);
            const float hav = fmaf(sla, sla, (pi.w * pj.w) * (slo*slo));
            const bool pos = (hav < A_POS) && (gi != gj);
            const bool neg = (hav > A_NEG);
            sEnc[(size_t)gi*NB + gj] = neg ? d2v : BIGV;
            sRed[rl][wc*16 + lr] = pos ? d2v : -1.f;
        }
    }
    __syncthreads();
    if (tid < 64) {
        float m = sRed[tid][0];
        #pragma unroll
        for (int c = 1; c < 32; ++c) m = fmaxf(m, sRed[tid][c]);
        pP[(i0 + tid)*32 + jb] = m;
    }
}

// K2: per-row finalize + last-block loss emit (r13-proven pattern).
__global__ __launch_bounds__(256) void rows_final(
    const float* __restrict__ sEnc, const float* __restrict__ pP,
    float* __restrict__ flags, float* __restrict__ out)
{
    __shared__ float sT[4], sV[4];
    const int tid = threadIdx.x, lane = tid & 63, w = tid >> 6;
    const int i = blockIdx.x*4 + w;

    float p = pP[i*32 + (lane & 31)];
    #pragma unroll
    for (int off = 1; off < 32; off <<= 1) p = fmaxf(p, __shfl_xor(p, off));
    const float dap2 = p;
    const bool has_pos = dap2 > -0.5f;
    float lo2 = -1.f, hi2 = -1.f;
    if (has_pos) { const float hb = sqrtf(dap2) + MARGINF; lo2 = dap2; hi2 = hb*hb; }

    float nmin = BIGV, smin = BIGV;
    const float4* __restrict__ row = (const float4*)sEnc + (size_t)i*256;
    #pragma unroll
    for (int pss = 0; pss < 4; ++pss) {
        const float4 x = row[pss*64 + lane];
        #pragma unroll
        for (int q = 0; q < 4; ++q) {
            const float xc = (q==0) ? x.x : (q==1) ? x.y : (q==2) ? x.z : x.w;
            nmin = fminf(nmin, xc);
            smin = fminf(smin, (xc > lo2 && xc < hi2) ? xc : BIGV);
        }
    }
    #pragma unroll
    for (int off = 1; off < 64; off <<= 1) {
        nmin = fminf(nmin, __shfl_xor(nmin, off));
        smin = fminf(smin, __shfl_xor(smin, off));
    }
    if (lane == 0) {
        const bool has_neg  = nmin < 0.5f*BIGV;
        const bool has_semi = smin < 0.5f*BIGV;
        const float dan2 = has_semi ? smin : nmin;
        const float dap  = has_pos ? sqrtf(dap2) : 0.f;
        float t = dap - sqrtf(dan2) + MARGINF;
        t = t > 0.f ? t : 0.f;
        const bool valid = has_pos && has_neg;
        sT[w] = valid ? t : 0.f;
        sV[w] = valid ? 1.f : 0.f;
    }
    __syncthreads();
    if (tid == 0) {
        atomicAdd(&flags[0], sT[0]+sT[1]+sT[2]+sT[3]);
        atomicAdd(&flags[1], sV[0]+sV[1]+sV[2]+sV[3]);
        __threadfence();
        const unsigned old = atomicAdd((unsigned*)&flags[2], 1u);
        if (old == 255u) {             // last block (order-independent)
            const float t = atomicAdd(&flags[0], 0.f);
            const float v = atomicAdd(&flags[1], 0.f);
            out[0] = t / fmaxf(v, 1.f);
        }
    }
}

extern "C" void kernel_launch(void* const* d_in, const int* in_sizes, int n_in,
                              void* d_out, int out_size, void* d_ws, size_t ws_size,
                              hipStream_t stream) {
    const float* emb = (const float*)d_in[0];   // [1024,256] f32
    const float* gps = (const float*)d_in[1];   // [1024,2]  f32
    float* ws = (float*)d_ws;                   // ws is ~256 MB (r8-r14 fills)

    float*          sEnc  = ws;                         // 1024*1024 f32 = 4 MB
    unsigned short* Hp    = (unsigned short*)(ws + 1048576);        // 512 KB
    unsigned short* Lp    = (unsigned short*)(ws + 1048576 + 131072); // 512 KB
    float4*         prep  = (float4*)(ws + 1048576 + 262144);       // 16 KB
    float*          pP    = ws + 1048576 + 262144 + 4096;           // 1024*32
    float*          flags = pP + 32768;                             // 3 floats

    prep_kernel<<<64, 256, 0, stream>>>(emb, gps, Hp, Lp, prep, flags);
    gram_mfma<<<512, 256, 0, stream>>>(Hp, Lp, prep, sEnc, pP);
    rows_final<<<256, 256, 0, stream>>>(sEnc, pP, flags, (float*)d_out);
}

// Round 16
// 35.716 us; speedup vs baseline: 1.8837x; 1.0823x over previous
//
#include <hip/hip_runtime.h>
#include <hip/hip_bf16.h>

typedef __attribute__((ext_vector_type(8))) short bf16x8;
typedef __attribute__((ext_vector_type(4))) float f32x4;

#define NB 1024
#define ND 256
#define MARGINF 0.3f
#define BIGV 1e9f
#define D2R 0.017453292519943295f
#define HD2R 0.008726646259971648f

// haversine 'a' thresholds: sin^2(T/(2*6371000)) (validated rounds 1-15)
#define A_POS 3.8495040e-12f   // 25 m
#define A_NEG 6.1592064e-11f   // 100 m

__device__ __forceinline__ float d4(float4 a, float4 b, float acc) {
    return fmaf(a.x,b.x, fmaf(a.y,b.y, fmaf(a.z,b.z, fmaf(a.w,b.w, acc))));
}

__device__ __forceinline__ void splitHL(float4 v0, float4 v1, bf16x8& H, bf16x8& L) {
    float f[8] = {v0.x, v0.y, v0.z, v0.w, v1.x, v1.y, v1.z, v1.w};
    #pragma unroll
    for (int q = 0; q < 8; ++q) {
        __hip_bfloat16 h = __float2bfloat16(f[q]);
        float hf = __bfloat162float(h);
        __hip_bfloat16 l = __float2bfloat16(f[q] - hf);
        H[q] = *(short*)&h;
        L[q] = *(short*)&l;
    }
}

// K1: r11-exact MFMA gram (best measured: 27.4 us total in 3-node config).
// 64x64 tile, 256 thr, 2x2 waves, acc[2][2]; in-register H/L split feeds the
// MFMA shadow; G = HH' + LH' + HL'; d^2 = sq_i + sq_j - 2G (exact fp32 norms).
// Block 0 additionally zeroes the flags cells for K2 (read only after this
// kernel completes -> no race).
__global__ __launch_bounds__(256) void gram_mfma(
    const float* __restrict__ emb, const float* __restrict__ gps,
    float* __restrict__ sEnc, float* __restrict__ pP, float* __restrict__ flags)
{
    __shared__ float  sSqI[64], sSqJ[64];
    __shared__ float4 sGI[64], sGJ[64];
    __shared__ float  sRed[64][33];

    const int tid = threadIdx.x, lane = tid & 63, w = tid >> 6;
    const int wr = w >> 1, wc = w & 1;
    const int ib = blockIdx.x & 15, jb = blockIdx.x >> 4;
    const int i0 = ib*64, j0 = jb*64;
    const int lr = lane & 15, lk = lane >> 4;
    const float4* __restrict__ emb4 = (const float4*)emb;

    if (blockIdx.x == 0 && tid < 3) flags[tid] = 0.f;   // gsum, gcnt, done

    // prologue: row norms (exact fp32) + gps scalars
    {
        const int half = tid & 1, r = (tid >> 1) & 63;
        const int base = (tid < 128) ? i0 : j0;
        const float4* rp = emb4 + (size_t)(base + r)*64 + half*32;
        float s = 0.f;
        #pragma unroll
        for (int q = 0; q < 32; ++q) s = d4(rp[q], rp[q], s);
        s += __shfl_xor(s, 1);
        if (half == 0) { if (tid < 128) sSqI[r] = s; else sSqJ[r] = s; }
    }
    if (tid < 128) {
        const int r = tid & 63;
        const int base = (tid < 64) ? i0 : j0;
        float2 g = ((const float2*)gps)[base + r];
        float4 gi = make_float4(g.x, g.y, cosf(g.x * D2R), 0.f);
        if (tid < 64) sGI[r] = gi; else sGJ[r] = gi;
    }
    __syncthreads();

    // MFMA loop: 8 k-windows x {8 loads -> 4 splits -> 12 MFMAs}
    f32x4 acc[2][2] = {};
    #pragma unroll 2
    for (int k8 = 0; k8 < 8; ++k8) {
        const int co = k8*8 + lk*2;
        const float4* pa0 = emb4 + (size_t)(i0 + wr*32      + lr)*64 + co;
        const float4* pa1 = emb4 + (size_t)(i0 + wr*32 + 16 + lr)*64 + co;
        const float4* pb0 = emb4 + (size_t)(j0 + wc*32      + lr)*64 + co;
        const float4* pb1 = emb4 + (size_t)(j0 + wc*32 + 16 + lr)*64 + co;
        bf16x8 a0H,a0L,a1H,a1L,b0H,b0L,b1H,b1L;
        splitHL(pa0[0], pa0[1], a0H, a0L);
        splitHL(pa1[0], pa1[1], a1H, a1L);
        splitHL(pb0[0], pb0[1], b0H, b0L);
        splitHL(pb1[0], pb1[1], b1H, b1L);
        acc[0][0] = __builtin_amdgcn_mfma_f32_16x16x32_bf16(a0H, b0H, acc[0][0], 0,0,0);
        acc[0][1] = __builtin_amdgcn_mfma_f32_16x16x32_bf16(a0H, b1H, acc[0][1], 0,0,0);
        acc[1][0] = __builtin_amdgcn_mfma_f32_16x16x32_bf16(a1H, b0H, acc[1][0], 0,0,0);
        acc[1][1] = __builtin_amdgcn_mfma_f32_16x16x32_bf16(a1H, b1H, acc[1][1], 0,0,0);
        acc[0][0] = __builtin_amdgcn_mfma_f32_16x16x32_bf16(a0L, b0H, acc[0][0], 0,0,0);
        acc[0][1] = __builtin_amdgcn_mfma_f32_16x16x32_bf16(a0L, b1H, acc[0][1], 0,0,0);
        acc[1][0] = __builtin_amdgcn_mfma_f32_16x16x32_bf16(a1L, b0H, acc[1][0], 0,0,0);
        acc[1][1] = __builtin_amdgcn_mfma_f32_16x16x32_bf16(a1L, b1H, acc[1][1], 0,0,0);
        acc[0][0] = __builtin_amdgcn_mfma_f32_16x16x32_bf16(a0H, b0L, acc[0][0], 0,0,0);
        acc[0][1] = __builtin_amdgcn_mfma_f32_16x16x32_bf16(a0H, b1L, acc[0][1], 0,0,0);
        acc[1][0] = __builtin_amdgcn_mfma_f32_16x16x32_bf16(a1H, b0L, acc[1][0], 0,0,0);
        acc[1][1] = __builtin_amdgcn_mfma_f32_16x16x32_bf16(a1H, b1L, acc[1][1], 0,0,0);
    }

    // epilogue: d^2, masks, sEnc encode, per-row pmax partials
    float sqj[2]; float4 gj2[2];
    sqj[0] = sSqJ[wc*32 + lr];      gj2[0] = sGJ[wc*32 + lr];
    sqj[1] = sSqJ[wc*32 + 16 + lr]; gj2[1] = sGJ[wc*32 + 16 + lr];

    #pragma unroll
    for (int fi = 0; fi < 2; ++fi) {
        #pragma unroll
        for (int r = 0; r < 4; ++r) {
            const int rl = wr*32 + fi*16 + lk*4 + r;
            const int gi = i0 + rl;
            const float sqi = sSqI[rl];
            const float4 gvi = sGI[rl];
            float pmax = -1.f;
            #pragma unroll
            for (int fj = 0; fj < 2; ++fj) {
                const int gj = j0 + wc*32 + fj*16 + lr;
                float d2v = sqi + sqj[fj] - 2.f*acc[fi][fj][r];
                d2v = d2v > 0.f ? d2v : 0.f;
                const float sla = sinf((gj2[fj].x - gvi.x) * HD2R);
                const float slo = sinf((gj2[fj].y - gvi.y) * HD2R);
                const float hav = fmaf(sla, sla, (gvi.z * gj2[fj].z) * (slo*slo));
                const bool pos = (hav < A_POS) && (gi != gj);
                const bool neg = (hav > A_NEG);
                pmax = fmaxf(pmax, pos ? d2v : -1.f);
                sEnc[(size_t)gi*NB + gj] = neg ? d2v : BIGV;
            }
            sRed[rl][lr + 16*wc] = pmax;
        }
    }
    __syncthreads();
    if (tid < 64) {
        float m = sRed[tid][0];
        #pragma unroll
        for (int c = 1; c < 32; ++c) m = fmaxf(m, sRed[tid][c]);
        pP[(i0 + tid)*16 + jb] = m;
    }
}

// K2: per-row finalize + last-block loss emit (r13/r15-proven pattern).
__global__ __launch_bounds__(256) void rows_final(
    const float* __restrict__ sEnc, const float* __restrict__ pP,
    float* __restrict__ flags, float* __restrict__ out)
{
    __shared__ float sT[4], sV[4];
    const int tid = threadIdx.x, lane = tid & 63, w = tid >> 6;
    const int i = blockIdx.x*4 + w;

    float p = pP[i*16 + (lane & 15)];
    #pragma unroll
    for (int off = 1; off < 16; off <<= 1) p = fmaxf(p, __shfl_xor(p, off));
    const float dap2 = p;
    const bool has_pos = dap2 > -0.5f;
    float lo2 = -1.f, hi2 = -1.f;
    if (has_pos) { const float hb = sqrtf(dap2) + MARGINF; lo2 = dap2; hi2 = hb*hb; }

    float nmin = BIGV, smin = BIGV;
    const float4* __restrict__ row = (const float4*)sEnc + (size_t)i*256;
    #pragma unroll
    for (int pss = 0; pss < 4; ++pss) {
        const float4 x = row[pss*64 + lane];
        #pragma unroll
        for (int q = 0; q < 4; ++q) {
            const float xc = (q==0) ? x.x : (q==1) ? x.y : (q==2) ? x.z : x.w;
            nmin = fminf(nmin, xc);
            smin = fminf(smin, (xc > lo2 && xc < hi2) ? xc : BIGV);
        }
    }
    #pragma unroll
    for (int off = 1; off < 64; off <<= 1) {
        nmin = fminf(nmin, __shfl_xor(nmin, off));
        smin = fminf(smin, __shfl_xor(smin, off));
    }
    if (lane == 0) {
        const bool has_neg  = nmin < 0.5f*BIGV;
        const bool has_semi = smin < 0.5f*BIGV;
        const float dan2 = has_semi ? smin : nmin;
        const float dap  = has_pos ? sqrtf(dap2) : 0.f;
        float t = dap - sqrtf(dan2) + MARGINF;
        t = t > 0.f ? t : 0.f;
        const bool valid = has_pos && has_neg;
        sT[w] = valid ? t : 0.f;
        sV[w] = valid ? 1.f : 0.f;
    }
    __syncthreads();
    if (tid == 0) {
        atomicAdd(&flags[0], sT[0]+sT[1]+sT[2]+sT[3]);
        atomicAdd(&flags[1], sV[0]+sV[1]+sV[2]+sV[3]);
        __threadfence();
        const unsigned old = atomicAdd((unsigned*)&flags[2], 1u);
        if (old == 255u) {             // last block (order-independent)
            const float t = atomicAdd(&flags[0], 0.f);
            const float v = atomicAdd(&flags[1], 0.f);
            out[0] = t / fmaxf(v, 1.f);
        }
    }
}

extern "C" void kernel_launch(void* const* d_in, const int* in_sizes, int n_in,
                              void* d_out, int out_size, void* d_ws, size_t ws_size,
                              hipStream_t stream) {
    const float* emb = (const float*)d_in[0];   // [1024,256] f32
    const float* gps = (const float*)d_in[1];   // [1024,2]  f32
    float* ws = (float*)d_ws;

    float* sEnc  = ws;                    // 1024*1024 f32 = 4 MB
    float* pP    = ws + 1048576;          // 1024*16
    float* flags = pP + 16384;            // {gsum, gcnt, done}

    gram_mfma<<<256, 256, 0, stream>>>(emb, gps, sEnc, pP, flags);
    rows_final<<<256, 256, 0, stream>>>(sEnc, pP, flags, (float*)d_out);
}

// Round 17
// 27.776 us; speedup vs baseline: 2.4222x; 1.2859x over previous
//
#include <hip/hip_runtime.h>
#include <hip/hip_bf16.h>

typedef __attribute__((ext_vector_type(8))) short bf16x8;
typedef __attribute__((ext_vector_type(4))) float f32x4;

#define NB 1024
#define ND 256
#define MARGINF 0.3f
#define BIGV 1e9f
#define D2R 0.017453292519943295f
#define HD2R 0.008726646259971648f

// haversine 'a' thresholds: sin^2(T/(2*6371000)) (validated rounds 1-16)
#define A_POS 3.8495040e-12f   // 25 m
#define A_NEG 6.1592064e-11f   // 100 m

__device__ __forceinline__ float d4(float4 a, float4 b, float acc) {
    return fmaf(a.x,b.x, fmaf(a.y,b.y, fmaf(a.z,b.z, fmaf(a.w,b.w, acc))));
}

__device__ __forceinline__ void splitHL(float4 v0, float4 v1, bf16x8& H, bf16x8& L) {
    float f[8] = {v0.x, v0.y, v0.z, v0.w, v1.x, v1.y, v1.z, v1.w};
    #pragma unroll
    for (int q = 0; q < 8; ++q) {
        __hip_bfloat16 h = __float2bfloat16(f[q]);
        float hf = __bfloat162float(h);
        __hip_bfloat16 l = __float2bfloat16(f[q] - hf);
        H[q] = *(short*)&h;
        L[q] = *(short*)&l;
    }
}

// K1: r11's gram with K-SPLIT occupancy: 512 thr / 8 waves, 2 waves/SIMD.
// Wave quadrant wq=(w&3) -> same 32x32 output as r11 (acc[2][2], 12 MFMA : 4
// splitHL per k-window); k-half kh=(w>>2) -> waves do 4 of the 8 k-windows.
// Partial accs combined once through padded LDS; epilogue split by fi=kh.
__global__ __launch_bounds__(512, 2) void gram_mfma(
    const float* __restrict__ emb, const float* __restrict__ gps,
    float* __restrict__ sEnc, float* __restrict__ pP)
{
    __shared__ float  sSqI[64], sSqJ[64];
    __shared__ float4 sGI[64], sGJ[64];
    __shared__ float  sRed[64][33];
    __shared__ float  sAcc[4*64*17];   // stride 17 floats: conflict-free lane*17

    const int tid = threadIdx.x, lane = tid & 63, w = tid >> 6;
    const int wq = w & 3, kh = w >> 2;             // quadrant, k-half
    const int wr = wq >> 1, wc = wq & 1;
    const int ib = blockIdx.x & 15, jb = blockIdx.x >> 4;
    const int i0 = ib*64, j0 = jb*64;
    const int lr = lane & 15, lk = lane >> 4;
    const float4* __restrict__ emb4 = (const float4*)emb;

    // ---- prologue: row norms (4 thr/row, exact fp32) + gps scalars ----
    {
        const int q4 = tid & 3, r = (tid >> 2) & 63;
        const int base = (tid < 256) ? i0 : j0;
        const float4* rp = emb4 + (size_t)(base + r)*64 + q4*16;
        float s = 0.f;
        #pragma unroll
        for (int q = 0; q < 16; ++q) s = d4(rp[q], rp[q], s);
        s += __shfl_xor(s, 1);
        s += __shfl_xor(s, 2);
        if (q4 == 0) { if (tid < 256) sSqI[r] = s; else sSqJ[r] = s; }
    }
    if (tid < 128) {
        const int r = tid & 63;
        const int base = (tid < 64) ? i0 : j0;
        float2 g = ((const float2*)gps)[base + r];
        float4 gi = make_float4(g.x, g.y, cosf(g.x * D2R), 0.f);
        if (tid < 64) sGI[r] = gi; else sGJ[r] = gi;
    }
    __syncthreads();

    // ---- MFMA loop: this wave's 4 k-windows (r11 body unchanged) ----
    f32x4 acc[2][2] = {};
    #pragma unroll 2
    for (int kk8 = 0; kk8 < 4; ++kk8) {
        const int k8 = kh*4 + kk8;
        const int co = k8*8 + lk*2;
        const float4* pa0 = emb4 + (size_t)(i0 + wr*32      + lr)*64 + co;
        const float4* pa1 = emb4 + (size_t)(i0 + wr*32 + 16 + lr)*64 + co;
        const float4* pb0 = emb4 + (size_t)(j0 + wc*32      + lr)*64 + co;
        const float4* pb1 = emb4 + (size_t)(j0 + wc*32 + 16 + lr)*64 + co;
        bf16x8 a0H,a0L,a1H,a1L,b0H,b0L,b1H,b1L;
        splitHL(pa0[0], pa0[1], a0H, a0L);
        splitHL(pa1[0], pa1[1], a1H, a1L);
        splitHL(pb0[0], pb0[1], b0H, b0L);
        splitHL(pb1[0], pb1[1], b1H, b1L);
        acc[0][0] = __builtin_amdgcn_mfma_f32_16x16x32_bf16(a0H, b0H, acc[0][0], 0,0,0);
        acc[0][1] = __builtin_amdgcn_mfma_f32_16x16x32_bf16(a0H, b1H, acc[0][1], 0,0,0);
        acc[1][0] = __builtin_amdgcn_mfma_f32_16x16x32_bf16(a1H, b0H, acc[1][0], 0,0,0);
        acc[1][1] = __builtin_amdgcn_mfma_f32_16x16x32_bf16(a1H, b1H, acc[1][1], 0,0,0);
        acc[0][0] = __builtin_amdgcn_mfma_f32_16x16x32_bf16(a0L, b0H, acc[0][0], 0,0,0);
        acc[0][1] = __builtin_amdgcn_mfma_f32_16x16x32_bf16(a0L, b1H, acc[0][1], 0,0,0);
        acc[1][0] = __builtin_amdgcn_mfma_f32_16x16x32_bf16(a1L, b0H, acc[1][0], 0,0,0);
        acc[1][1] = __builtin_amdgcn_mfma_f32_16x16x32_bf16(a1L, b1H, acc[1][1], 0,0,0);
        acc[0][0] = __builtin_amdgcn_mfma_f32_16x16x32_bf16(a0H, b0L, acc[0][0], 0,0,0);
        acc[0][1] = __builtin_amdgcn_mfma_f32_16x16x32_bf16(a0H, b1L, acc[0][1], 0,0,0);
        acc[1][0] = __builtin_amdgcn_mfma_f32_16x16x32_bf16(a1H, b0L, acc[1][0], 0,0,0);
        acc[1][1] = __builtin_amdgcn_mfma_f32_16x16x32_bf16(a1H, b1L, acc[1][1], 0,0,0);
    }

    // ---- combine k-halves through LDS (exact fp32 add) ----
    float* ab = &sAcc[(wq*64 + lane)*17];
    if (kh == 1) {
        #pragma unroll
        for (int fi = 0; fi < 2; ++fi)
            #pragma unroll
            for (int fj = 0; fj < 2; ++fj)
                #pragma unroll
                for (int r = 0; r < 4; ++r)
                    ab[fi*8 + fj*4 + r] = acc[fi][fj][r];
    }
    __syncthreads();
    if (kh == 0) {
        #pragma unroll
        for (int fi = 0; fi < 2; ++fi)
            #pragma unroll
            for (int fj = 0; fj < 2; ++fj)
                #pragma unroll
                for (int r = 0; r < 4; ++r)
                    acc[fi][fj][r] += ab[fi*8 + fj*4 + r];
        #pragma unroll
        for (int fj = 0; fj < 2; ++fj)       // hand combined fi=1 half to partner
            #pragma unroll
            for (int r = 0; r < 4; ++r)
                ab[8 + fj*4 + r] = acc[1][fj][r];
    }
    __syncthreads();
    if (kh == 1) {
        #pragma unroll
        for (int fj = 0; fj < 2; ++fj)
            #pragma unroll
            for (int r = 0; r < 4; ++r)
                acc[1][fj][r] = ab[8 + fj*4 + r];
    }

    // ---- epilogue (split: wave handles fi = kh) ----
    float sqj[2]; float4 gj2[2];
    sqj[0] = sSqJ[wc*32 + lr];      gj2[0] = sGJ[wc*32 + lr];
    sqj[1] = sSqJ[wc*32 + 16 + lr]; gj2[1] = sGJ[wc*32 + 16 + lr];

    const int fi = kh;
    #pragma unroll
    for (int r = 0; r < 4; ++r) {
        const int rl = wr*32 + fi*16 + lk*4 + r;
        const int gi = i0 + rl;
        const float sqi = sSqI[rl];
        const float4 gvi = sGI[rl];
        float pmax = -1.f;
        #pragma unroll
        for (int fj = 0; fj < 2; ++fj) {
            const int gj = j0 + wc*32 + fj*16 + lr;
            float d2v = sqi + sqj[fj] - 2.f*acc[fi][fj][r];
            d2v = d2v > 0.f ? d2v : 0.f;
            const float sla = sinf((gj2[fj].x - gvi.x) * HD2R);
            const float slo = sinf((gj2[fj].y - gvi.y) * HD2R);
            const float hav = fmaf(sla, sla, (gvi.z * gj2[fj].z) * (slo*slo));
            const bool pos = (hav < A_POS) && (gi != gj);
            const bool neg = (hav > A_NEG);
            pmax = fmaxf(pmax, pos ? d2v : -1.f);
            sEnc[(size_t)gi*NB + gj] = neg ? d2v : BIGV;
        }
        sRed[rl][lr + 16*wc] = pmax;
    }
    __syncthreads();
    if (tid < 64) {
        float m = sRed[tid][0];
        #pragma unroll
        for (int c = 1; c < 32; ++c) m = fmaxf(m, sRed[tid][c]);
        pP[(i0 + tid)*16 + jb] = m;
    }
}

// K2: per-row finalize (r11-exact, plain stores)
__global__ __launch_bounds__(256) void rows_kernel(
    const float* __restrict__ sEnc, const float* __restrict__ pP,
    float* __restrict__ tri, float* __restrict__ val)
{
    const int tid = threadIdx.x, lane = tid & 63, w = tid >> 6;
    const int i = blockIdx.x*4 + w;

    float p = pP[i*16 + (lane & 15)];
    #pragma unroll
    for (int off = 1; off < 16; off <<= 1) p = fmaxf(p, __shfl_xor(p, off));
    const float dap2 = p;
    const bool has_pos = dap2 > -0.5f;
    float lo2 = -1.f, hi2 = -1.f;
    if (has_pos) { const float hb = sqrtf(dap2) + MARGINF; lo2 = dap2; hi2 = hb*hb; }

    float nmin = BIGV, smin = BIGV;
    const float4* __restrict__ row = (const float4*)sEnc + (size_t)i*256;
    #pragma unroll
    for (int pss = 0; pss < 4; ++pss) {
        const float4 x = row[pss*64 + lane];
        #pragma unroll
        for (int q = 0; q < 4; ++q) {
            const float xc = (q==0) ? x.x : (q==1) ? x.y : (q==2) ? x.z : x.w;
            nmin = fminf(nmin, xc);
            smin = fminf(smin, (xc > lo2 && xc < hi2) ? xc : BIGV);
        }
    }
    #pragma unroll
    for (int off = 1; off < 64; off <<= 1) {
        nmin = fminf(nmin, __shfl_xor(nmin, off));
        smin = fminf(smin, __shfl_xor(smin, off));
    }
    if (lane == 0) {
        const bool has_neg  = nmin < 0.5f*BIGV;
        const bool has_semi = smin < 0.5f*BIGV;
        const float dan2 = has_semi ? smin : nmin;
        const float dap  = has_pos ? sqrtf(dap2) : 0.f;
        float t = dap - sqrtf(dan2) + MARGINF;
        t = t > 0.f ? t : 0.f;
        const bool valid = has_pos && has_neg;
        tri[i] = valid ? t : 0.f;
        val[i] = valid ? 1.f : 0.f;
    }
}

__global__ __launch_bounds__(256) void finalize_kernel(
    const float* __restrict__ tri, const float* __restrict__ val, float* __restrict__ out)
{
    const int tid = threadIdx.x;
    float st = 0.f, sv = 0.f;
    #pragma unroll
    for (int g = 0; g < 4; ++g) { st += tri[tid + (g<<8)]; sv += val[tid + (g<<8)]; }
    #pragma unroll
    for (int off = 1; off < 64; off <<= 1) { st += __shfl_xor(st, off); sv += __shfl_xor(sv, off); }
    __shared__ float rt[4], rv[4];
    if ((tid & 63) == 0) { rt[tid>>6] = st; rv[tid>>6] = sv; }
    __syncthreads();
    if (tid == 0) {
        float t = rt[0]+rt[1]+rt[2]+rt[3];
        float v = rv[0]+rv[1]+rv[2]+rv[3];
        out[0] = t / fmaxf(v, 1.f);
    }
}

extern "C" void kernel_launch(void* const* d_in, const int* in_sizes, int n_in,
                              void* d_out, int out_size, void* d_ws, size_t ws_size,
                              hipStream_t stream) {
    const float* emb = (const float*)d_in[0];   // [1024,256] f32
    const float* gps = (const float*)d_in[1];   // [1024,2]  f32
    float* ws = (float*)d_ws;

    float* sEnc = ws;                    // 1024*1024 f32 = 4 MB
    float* pP   = ws + 1048576;          // 1024*16
    float* tri  = pP + 16384;            // 1024
    float* val  = tri + 1024;            // 1024

    gram_mfma<<<256, 512, 0, stream>>>(emb, gps, sEnc, pP);
    rows_kernel<<<256, 256, 0, stream>>>(sEnc, pP, tri, val);
    finalize_kernel<<<1, 256, 0, stream>>>(tri, val, (float*)d_out);
}